// Round 5
// baseline (824.803 us; speedup 1.0000x reference)
//
#include <hip/hip_runtime.h>
#include <cstdint>
#include <cstddef>

// B=10, Hi=Wi=64, C=64, M=8, Hb=Wb=128, U=64.
// All-fp32 pipeline (bf16 conv fails: reference's rmask = (rw>0) flips at
// conv2 pre-activation zero-crossings; needs ~1e-6 accuracy -> fp32 VALU).
// conv1 v2: 3 output rows x 4 px x 4 u per thread -> FMA:LDS = 432:19 per ch.

// ---------------------------------------------------------------------------
// conv1_v2: 3x3 SAME conv, C=64 -> U=64, + bias + relu, fp32.
// Block = 256 threads (4 waves) -> output tile 3 rows x 64 px x 64 u.
// Thread: u0 = (tid&15)*4, x0 = (tid>>4)*4, 3 output rows.
// LDS per 8-ch chunk: input 5 rows x 66 px (stride 68), weights 9x8x64.
// INST: gathers from instance_feature [B,Hi,Wi,C,M] (fused transpose).
// ---------------------------------------------------------------------------
template<bool INST>
__global__ __launch_bounds__(256) void conv1_v2(const float* __restrict__ src,
    const float* __restrict__ w, const float* __restrict__ bias,
    float* __restrict__ dst, int N, int H, int W)
{
  __shared__ __align__(16) float in_s[5 * 8 * 68];   // [ir][c][xi], stride 68
  __shared__ __align__(16) float w_s[9 * 8 * 64];    // [k9][c][u]

  const int tid = threadIdx.x;
  const int tilesX = W >> 6;
  const int RG = (H + 2) / 3;
  const int bid = blockIdx.x;
  const int xt = bid % tilesX;
  const int t2 = bid / tilesX;
  const int rg = t2 % RG;
  const int n = t2 / RG;
  const int yb = rg * 3;
  const int xb = xt << 6;

  const int u0 = (tid & 15) << 2;
  const int x0 = (tid >> 4) << 2;

  float acc[3][4][4];
  #pragma unroll
  for (int yo = 0; yo < 3; ++yo)
    #pragma unroll
    for (int i = 0; i < 4; ++i)
      #pragma unroll
      for (int j = 0; j < 4; ++j)
        acc[yo][i][j] = 0.f;

  int b = 0, m = 0;
  if (INST) { b = n >> 3; m = n & 7; }

  for (int cc = 0; cc < 8; ++cc) {
    const int c0 = cc * 8;
    __syncthreads();  // protect LDS from previous chunk's readers
    // ---- stage input: rows yb-1..yb+3, x in [xb-1, xb+64], channels c0..c0+7
    for (int e = tid; e < 2640; e += 256) {
      int cl = e & 7;
      int q = e >> 3;
      int xi = q % 66;
      int ir = q / 66;
      int gy = yb + ir - 1;
      int gx = xb + xi - 1;
      float v = 0.f;
      if (gy >= 0 && gy < H && gx >= 0 && gx < W) {
        if (INST) {
          v = src[(size_t)b * 2097152 + (size_t)gy * 32768 + (size_t)gx * 512
                  + (size_t)(c0 + cl) * 8 + m];
        } else {
          v = src[((size_t)(n * H + gy) * W + gx) * 64 + c0 + cl];
        }
      }
      in_s[(ir * 8 + cl) * 68 + xi] = v;
    }
    // ---- stage weights: w[k9][c0+c][u]
    for (int e = tid; e < 4608; e += 256) {
      int u = e & 63;
      int q = e >> 6;       // k9*8 + c
      int c = q & 7;
      int k9 = q >> 3;
      w_s[q * 64 + u] = w[((size_t)k9 * 64 + c0 + c) * 64 + u];
    }
    __syncthreads();

    // ---- accumulate: per channel, 9 w-vectors in regs, 5 input rows
    for (int c = 0; c < 8; ++c) {
      float4 wr[9];
      #pragma unroll
      for (int t = 0; t < 9; ++t)
        wr[t] = *(const float4*)&w_s[(t * 8 + c) * 64 + u0];
      #pragma unroll
      for (int ir = 0; ir < 5; ++ir) {
        const float* rp = &in_s[(ir * 8 + c) * 68 + x0];
        float4 ra = *(const float4*)rp;        // 16B-aligned (68 % 4 == 0)
        float2 rb = *(const float2*)(rp + 4);
        float r[6] = {ra.x, ra.y, ra.z, ra.w, rb.x, rb.y};
        #pragma unroll
        for (int dy = 0; dy < 3; ++dy) {
          const int yo = ir - dy;
          if (yo < 0 || yo > 2) continue;      // folds at compile time
          #pragma unroll
          for (int dx = 0; dx < 3; ++dx) {
            float4 wv = wr[dy * 3 + dx];
            #pragma unroll
            for (int i = 0; i < 4; ++i) {
              float rv = r[i + dx];
              acc[yo][i][0] += rv * wv.x;
              acc[yo][i][1] += rv * wv.y;
              acc[yo][i][2] += rv * wv.z;
              acc[yo][i][3] += rv * wv.w;
            }
          }
        }
      }
    }
  }

  float4 bv = *(const float4*)&bias[u0];
  #pragma unroll
  for (int yo = 0; yo < 3; ++yo) {
    const int gy = yb + yo;
    if (gy < H) {
      #pragma unroll
      for (int i = 0; i < 4; ++i) {
        float4 o;
        o.x = fmaxf(acc[yo][i][0] + bv.x, 0.f);
        o.y = fmaxf(acc[yo][i][1] + bv.y, 0.f);
        o.z = fmaxf(acc[yo][i][2] + bv.z, 0.f);
        o.w = fmaxf(acc[yo][i][3] + bv.w, 0.f);
        *(float4*)&dst[((size_t)(n * H + gy) * W + (xb + x0 + i)) * 64 + u0] = o;
      }
    }
  }
}

// ---------------------------------------------------------------------------
// conv2: 3x3 SAME conv, 64 -> 1 ch, + bias + relu, fp32 (round-1 proven).
// ---------------------------------------------------------------------------
__global__ __launch_bounds__(256) void conv2_k(const float* __restrict__ hsrc,
    const float* __restrict__ w2, const float* __restrict__ b2,
    float* __restrict__ dst, int N, int H, int W)
{
  const int RS = 24;
  const int CS = 18 * 24 + 1;  // 433
  __shared__ float s[32 * (18 * 24 + 1)];
  __shared__ float wsm[576];

  const int tid = threadIdx.x;
  const int tilesX = W >> 4;
  const int bid = blockIdx.x;
  const int xt = bid % tilesX;
  const int q0 = bid / tilesX;
  const int yt = q0 % (H >> 4);
  const int n = q0 / (H >> 4);
  const int xb = xt << 4, yb = yt << 4;
  const int tx = tid & 15, ty = tid >> 4;

  for (int e = tid; e < 576; e += 256) wsm[e] = w2[e];

  float acc = 0.f;
  for (int cc = 0; cc < 2; ++cc) {
    const int c0 = cc << 5;
    if (cc) __syncthreads();
    for (int e = tid; e < 18 * 18 * 32; e += 256) {
      int c = e & 31;
      int p = e >> 5;
      int xx = p % 18;
      int yy = p / 18;
      int gy = yb + yy - 1, gx = xb + xx - 1;
      float v = 0.f;
      if (gy >= 0 && gy < H && gx >= 0 && gx < W)
        v = hsrc[((size_t)(n * H + gy) * W + gx) * 64 + c0 + c];
      s[c * CS + yy * RS + xx] = v;
    }
    __syncthreads();
    for (int c = 0; c < 32; ++c) {
      const float* sp = &s[c * CS + ty * RS + tx];
      const float* wp = &wsm[c0 + c];
      #pragma unroll
      for (int dy = 0; dy < 3; ++dy)
        #pragma unroll
        for (int dx = 0; dx < 3; ++dx)
          acc += sp[dy * RS + dx] * wp[(dy * 3 + dx) * 64];
    }
  }
  float bv = b2[0];
  dst[((size_t)n * H + yb + ty) * W + xb + tx] = fmaxf(acc + bv, 0.f);
}

// ---------------------------------------------------------------------------
// compose: fused resize_and_pad + masked-exp softmax composition (proven).
// ---------------------------------------------------------------------------
__global__ __launch_bounds__(256) void compose_k(const float* __restrict__ IF,
    const float* __restrict__ bg, const float* __restrict__ bbox,
    const int* __restrict__ objn, const float* __restrict__ instw,
    const float* __restrict__ bgw, float* __restrict__ out)
{
  const int tid = threadIdx.x;
  const int c = tid & 63;
  const int pid = blockIdx.x * 4 + (tid >> 6);  // b*16384 + h*128 + w
  const int b = pid >> 14;
  const int rem = pid & 16383;
  const int hh = rem >> 7;
  const int www = rem & 127;

  const float ebg = expf(bgw[pid]);
  const float bgc = bg[(size_t)pid * 64 + c];
  float acc = ebg * bgc;
  float denom = ebg;
  const int nobj = objn[b];

  #pragma unroll
  for (int m = 0; m < 8; ++m) {
    if (m >= nobj) continue;
    const float y0b = bbox[b * 32 + m];
    const float y1b = bbox[b * 32 + 8 + m];
    const float x0b = bbox[b * 32 + 16 + m];
    const float x1b = bbox[b * 32 + 24 + m];
    const float ysz = floorf(128.f * (y1b - y0b));
    const float xsz = floorf(128.f * (x1b - x0b));
    const float yf = floorf(128.f * y0b);
    const float xf = floorf(128.f * x0b);
    const float ly = (float)hh - yf;
    const float lx = (float)www - xf;
    if (!(ly >= 0.f && ly < ysz && lx >= 0.f && lx < xsz)) continue;
    float sy = (ly + 0.5f) * 64.f / fmaxf(ysz, 1.f) - 0.5f;
    float sx = (lx + 0.5f) * 64.f / fmaxf(xsz, 1.f) - 0.5f;
    sy = fminf(fmaxf(sy, 0.f), 63.f);
    sx = fminf(fmaxf(sx, 0.f), 63.f);
    const int y0i = (int)floorf(sy);
    const int x0i = (int)floorf(sx);
    const int y1i = min(y0i + 1, 63);
    const int x1i = min(x0i + 1, 63);
    const float wy = sy - (float)y0i;
    const float wx = sx - (float)x0i;
    const float omwx = 1.f - wx, omwy = 1.f - wy;

    const float* iw = instw + (size_t)(b * 8 + m) * 4096;
    const float v00 = iw[y0i * 64 + x0i];
    const float v01 = iw[y0i * 64 + x1i];
    const float v10 = iw[y1i * 64 + x0i];
    const float v11 = iw[y1i * 64 + x1i];
    const float rwv = (v00 * omwx + v01 * wx) * omwy + (v10 * omwx + v11 * wx) * wy;
    if (!(rwv > 0.f)) continue;   // rmask
    const float e = expf(rwv);
    denom += e;

    const float* fb = IF + (size_t)b * 2097152 + (size_t)c * 8 + m;
    const float t00 = fb[(size_t)y0i * 32768 + (size_t)x0i * 512];
    const float t01 = fb[(size_t)y0i * 32768 + (size_t)x1i * 512];
    const float t10 = fb[(size_t)y1i * 32768 + (size_t)x0i * 512];
    const float t11 = fb[(size_t)y1i * 32768 + (size_t)x1i * 512];
    const float bil = (t00 * omwx + t01 * wx) * omwy + (t10 * omwx + t11 * wx) * wy;
    acc += e * bil;
  }
  out[(size_t)pid * 64 + c] = acc / denom;
}

// ---------------------------------------------------------------------------
extern "C" void kernel_launch(void* const* d_in, const int* in_sizes, int n_in,
                              void* d_out, int out_size, void* d_ws, size_t ws_size,
                              hipStream_t stream)
{
  const float* IF   = (const float*)d_in[0];   // [10,64,64,64,8]
  const float* BG   = (const float*)d_in[1];   // [10,128,128,64]
  const float* BBOX = (const float*)d_in[2];   // [10,4,8]
  // d_in[3] mrcnn_mask: unused by the reference forward
  const float* w1i = (const float*)d_in[4];
  const float* b1i = (const float*)d_in[5];
  const float* w2i = (const float*)d_in[6];
  const float* b2i = (const float*)d_in[7];
  const float* w1b = (const float*)d_in[8];
  const float* b1b = (const float*)d_in[9];
  const float* w2b = (const float*)d_in[10];
  const float* b2b = (const float*)d_in[11];
  const int* objn  = (const int*)d_in[12];
  float* out = (float*)d_out;

  float* ws    = (float*)d_ws;
  float* hbuf  = ws;                      // max(80*64*64*64, 10*128*128*64) = 20,971,520 f
  float* instw = ws + 20971520;           // 80*64*64 = 327,680 f
  float* bgwp  = instw + 327680;          // 10*128*128 = 163,840 f

  // instance branch: conv1 (fused transpose) -> conv2
  conv1_v2<true><<<80 * 22, 256, 0, stream>>>(IF, w1i, b1i, hbuf, 80, 64, 64);
  conv2_k<<<80 * 4 * 4, 256, 0, stream>>>(hbuf, w2i, b2i, instw, 80, 64, 64);
  // bg branch (reuses hbuf; stream order serializes with conv2 above)
  conv1_v2<false><<<10 * 43 * 2, 256, 0, stream>>>(BG, w1b, b1b, hbuf, 10, 128, 128);
  conv2_k<<<10 * 8 * 8, 256, 0, stream>>>(hbuf, w2b, b2b, bgwp, 10, 128, 128);
  // fused resize + softmax composition
  compose_k<<<163840 / 4, 256, 0, stream>>>(IF, BG, BBOX, objn, instw, bgwp, out);
}

// Round 6
// 819.896 us; speedup vs baseline: 1.0060x; 1.0060x over previous
//
#include <hip/hip_runtime.h>
#include <cstdint>
#include <cstddef>

// B=10, Hi=Wi=64, C=64, M=8, Hb=Wb=128, U=64.
// conv1: fp32-accurate implicit GEMM on the MFMA pipe via 3-way bf16 split
// (hi/mid/lo, 6 partial products -> err ~1e-7 split + ~1e-6 fp32-accum, same
// class as the passing all-fp32 kernel; required because rmask=(rw>0) flips
// at conv2 pre-activation zero crossings). h1 stays fp32. conv2/compose fp32.

typedef __attribute__((ext_vector_type(8))) short short8;
typedef __attribute__((ext_vector_type(4))) float f32x4;

__device__ __forceinline__ unsigned short f2bf(float x) {
  union { float f; unsigned int u; } v; v.f = x;
  unsigned int r = (v.u + 0x7FFFu + ((v.u >> 16) & 1u)) >> 16;  // RNE
  return (unsigned short)r;
}
__device__ __forceinline__ float bf2f(unsigned short h) {
  union { unsigned int u; float f; } v; v.u = ((unsigned int)h) << 16;
  return v.f;
}
// fp32 -> 3x bf16 (24 mantissa bits captured exactly; residuals exact in fp32)
__device__ __forceinline__ void split3(float v, unsigned short& h,
                                       unsigned short& m, unsigned short& l) {
  h = f2bf(v);
  float r1 = v - bf2f(h);
  m = f2bf(r1);
  float r2 = r1 - bf2f(m);
  l = f2bf(r2);
}

// ---------------------------------------------------------------------------
// prep_w3: w [3,3,64,64] HWIO fp32 -> three bf16 fragment-ordered planes:
// wB[s][((kc*4+ut)*64 + lane)*8 + i], k = kc*32 + (lane>>4)*8 + i,
// k9=k>>6, c=k&63, u = ut*16 + (lane&15).  Plane stride 36864 elements.
// ---------------------------------------------------------------------------
__global__ void prep_w3(const float* __restrict__ w, unsigned short* __restrict__ wB)
{
  int idx = blockIdx.x * 256 + threadIdx.x;
  if (idx >= 18 * 4 * 64 * 8) return;
  int i = idx & 7;
  int lane = (idx >> 3) & 63;
  int ut = (idx >> 9) & 3;
  int kc = idx >> 11;
  int k = kc * 32 + (lane >> 4) * 8 + i;
  int u = ut * 16 + (lane & 15);
  int k9 = k >> 6, c = k & 63;
  float v = w[((size_t)(k9 * 64 + c)) * 64 + u];
  unsigned short h, m, l;
  split3(v, h, m, l);
  wB[idx] = h;
  wB[36864 + idx] = m;
  wB[73728 + idx] = l;
}

// ---------------------------------------------------------------------------
// conv1_mfma3: fp32 NHWC-gather in -> fp32 out [N,H,W,64], 3x3 SAME + relu.
// Block = 1 output row x 64 px x 64 u, 4 waves (wave w: px [16w,16w+16)).
// Staging: read fp32 (INST: strided gather from IF[B,Hi,Wi,C,M]), split3 in
// register, pack 2 bf16 per b32 into 3 XOR-swizzled LDS planes (76 KB).
// K-loop: 18 kc x 4 ut x 6 MFMA (hi*hi, hi*mid, mid*hi, hi*lo, lo*hi, mid*mid).
// ---------------------------------------------------------------------------
template<bool INST>
__global__ __launch_bounds__(256) void conv1_mfma3(const float* __restrict__ src,
    const unsigned short* __restrict__ wB, const float* __restrict__ bias,
    float* __restrict__ H1, int N, int H, int W)
{
  __shared__ __align__(16) char lds[3][3 * 66 * 128];  // [split][row][xi][c]

  const int tid = threadIdx.x;
  const int tilesX = W >> 6;
  const int bid = blockIdx.x;
  const int xt = bid % tilesX;
  const int row = bid / tilesX;
  const int y = row % H;
  const int n = row / H;
  const int xb = xt << 6;

  int b = 0, m = 0;
  if (INST) { b = n >> 3; m = n & 7; }

  // ---- stage + split: rows y-1..y+1, x in [xb-1,xb+64], 64 ch (2 per iter)
  for (int e = tid; e < 6336; e += 256) {
    int cp = e & 31;           // channel pair
    int q = e >> 5;
    int xi = q % 66;
    int r = q / 66;
    int gy = y + r - 1, gx = xb + xi - 1;
    float v0 = 0.f, v1 = 0.f;
    if (gy >= 0 && gy < H && gx >= 0 && gx < W) {
      if (INST) {
        const float* p = src + (size_t)b * 2097152 + (size_t)gy * 32768
                             + (size_t)gx * 512 + (size_t)cp * 16 + m;
        v0 = p[0]; v1 = p[8];
      } else {
        const float* p = src + ((size_t)(n * H + gy) * W + gx) * 64 + cp * 2;
        v0 = p[0]; v1 = p[1];
      }
    }
    unsigned short h0, m0, l0, h1, m1, l1;
    split3(v0, h0, m0, l0);
    split3(v1, h1, m1, l1);
    int off = (((r * 66 + xi) << 7) + (cp << 2)) ^ ((xi & 7) << 4);
    *(unsigned int*)&lds[0][off] = (unsigned int)h0 | ((unsigned int)h1 << 16);
    *(unsigned int*)&lds[1][off] = (unsigned int)m0 | ((unsigned int)m1 << 16);
    *(unsigned int*)&lds[2][off] = (unsigned int)l0 | ((unsigned int)l1 << 16);
  }
  __syncthreads();

  const int wave = tid >> 6, lane = tid & 63;
  const int mrow = lane & 15, g = lane >> 4;

  f32x4 z = {0.f, 0.f, 0.f, 0.f};
  f32x4 acc[4] = {z, z, z, z};
  const short8* bp = (const short8*)wB;   // plane stride 4608 short8

  #pragma unroll
  for (int k9 = 0; k9 < 9; ++k9) {
    const int dy = k9 / 3, dx = k9 % 3;
    const int xi = wave * 16 + mrow + dx;
    const int swz = (xi & 7) << 4;
    #pragma unroll
    for (int ch = 0; ch < 2; ++ch) {
      const int base = ((((dy * 66 + xi) << 7) + ch * 64 + g * 16)) ^ swz;
      short8 ahi = *(const short8*)&lds[0][base];
      short8 ami = *(const short8*)&lds[1][base];
      short8 alo = *(const short8*)&lds[2][base];
      const int kc = k9 * 2 + ch;
      #pragma unroll
      for (int ut = 0; ut < 4; ++ut) {
        const int bi = (kc * 4 + ut) * 64 + lane;
        short8 bhi = bp[bi];
        short8 bmi = bp[4608 + bi];
        short8 blo = bp[9216 + bi];
        f32x4 a4 = acc[ut];
        a4 = __builtin_amdgcn_mfma_f32_16x16x32_bf16(ahi, bhi, a4, 0, 0, 0);
        a4 = __builtin_amdgcn_mfma_f32_16x16x32_bf16(ahi, bmi, a4, 0, 0, 0);
        a4 = __builtin_amdgcn_mfma_f32_16x16x32_bf16(ami, bhi, a4, 0, 0, 0);
        a4 = __builtin_amdgcn_mfma_f32_16x16x32_bf16(ahi, blo, a4, 0, 0, 0);
        a4 = __builtin_amdgcn_mfma_f32_16x16x32_bf16(alo, bhi, a4, 0, 0, 0);
        a4 = __builtin_amdgcn_mfma_f32_16x16x32_bf16(ami, bmi, a4, 0, 0, 0);
        acc[ut] = a4;
      }
    }
  }

  // ---- epilogue: D = {row=(lane>>4)*4+r (=px), col=lane&15 (=u)} (probe-
  // confirmed in rounds 2/3). fp32 h1 out.
  #pragma unroll
  for (int ut = 0; ut < 4; ++ut) {
    const int u = ut * 16 + mrow;
    const float bv = bias[u];
    #pragma unroll
    for (int r = 0; r < 4; ++r) {
      const int px = wave * 16 + g * 4 + r;
      H1[((((size_t)n * H + y) * W + xb + px) << 6) + u] = fmaxf(acc[ut][r] + bv, 0.f);
    }
  }
}

// ---------------------------------------------------------------------------
// conv2: 3x3 SAME conv, 64 -> 1 ch, + bias + relu, fp32 (proven).
// ---------------------------------------------------------------------------
__global__ __launch_bounds__(256) void conv2_k(const float* __restrict__ hsrc,
    const float* __restrict__ w2, const float* __restrict__ b2,
    float* __restrict__ dst, int N, int H, int W)
{
  const int RS = 24;
  const int CS = 18 * 24 + 1;  // 433
  __shared__ float s[32 * (18 * 24 + 1)];
  __shared__ float wsm[576];

  const int tid = threadIdx.x;
  const int tilesX = W >> 4;
  const int bid = blockIdx.x;
  const int xt = bid % tilesX;
  const int q0 = bid / tilesX;
  const int yt = q0 % (H >> 4);
  const int n = q0 / (H >> 4);
  const int xb = xt << 4, yb = yt << 4;
  const int tx = tid & 15, ty = tid >> 4;

  for (int e = tid; e < 576; e += 256) wsm[e] = w2[e];

  float acc = 0.f;
  for (int cc = 0; cc < 2; ++cc) {
    const int c0 = cc << 5;
    if (cc) __syncthreads();
    for (int e = tid; e < 18 * 18 * 32; e += 256) {
      int c = e & 31;
      int p = e >> 5;
      int xx = p % 18;
      int yy = p / 18;
      int gy = yb + yy - 1, gx = xb + xx - 1;
      float v = 0.f;
      if (gy >= 0 && gy < H && gx >= 0 && gx < W)
        v = hsrc[((size_t)(n * H + gy) * W + gx) * 64 + c0 + c];
      s[c * CS + yy * RS + xx] = v;
    }
    __syncthreads();
    for (int c = 0; c < 32; ++c) {
      const float* sp = &s[c * CS + ty * RS + tx];
      const float* wp = &wsm[c0 + c];
      #pragma unroll
      for (int dy = 0; dy < 3; ++dy)
        #pragma unroll
        for (int dx = 0; dx < 3; ++dx)
          acc += sp[dy * RS + dx] * wp[(dy * 3 + dx) * 64];
    }
  }
  float bv = b2[0];
  dst[((size_t)n * H + yb + ty) * W + xb + tx] = fmaxf(acc + bv, 0.f);
}

// ---------------------------------------------------------------------------
// compose: fused resize_and_pad + masked-exp softmax composition (proven).
// ---------------------------------------------------------------------------
__global__ __launch_bounds__(256) void compose_k(const float* __restrict__ IF,
    const float* __restrict__ bg, const float* __restrict__ bbox,
    const int* __restrict__ objn, const float* __restrict__ instw,
    const float* __restrict__ bgw, float* __restrict__ out)
{
  const int tid = threadIdx.x;
  const int c = tid & 63;
  const int pid = blockIdx.x * 4 + (tid >> 6);  // b*16384 + h*128 + w
  const int b = pid >> 14;
  const int rem = pid & 16383;
  const int hh = rem >> 7;
  const int www = rem & 127;

  const float ebg = expf(bgw[pid]);
  const float bgc = bg[(size_t)pid * 64 + c];
  float acc = ebg * bgc;
  float denom = ebg;
  const int nobj = objn[b];

  #pragma unroll
  for (int m = 0; m < 8; ++m) {
    if (m >= nobj) continue;
    const float y0b = bbox[b * 32 + m];
    const float y1b = bbox[b * 32 + 8 + m];
    const float x0b = bbox[b * 32 + 16 + m];
    const float x1b = bbox[b * 32 + 24 + m];
    const float ysz = floorf(128.f * (y1b - y0b));
    const float xsz = floorf(128.f * (x1b - x0b));
    const float yf = floorf(128.f * y0b);
    const float xf = floorf(128.f * x0b);
    const float ly = (float)hh - yf;
    const float lx = (float)www - xf;
    if (!(ly >= 0.f && ly < ysz && lx >= 0.f && lx < xsz)) continue;
    float sy = (ly + 0.5f) * 64.f / fmaxf(ysz, 1.f) - 0.5f;
    float sx = (lx + 0.5f) * 64.f / fmaxf(xsz, 1.f) - 0.5f;
    sy = fminf(fmaxf(sy, 0.f), 63.f);
    sx = fminf(fmaxf(sx, 0.f), 63.f);
    const int y0i = (int)floorf(sy);
    const int x0i = (int)floorf(sx);
    const int y1i = min(y0i + 1, 63);
    const int x1i = min(x0i + 1, 63);
    const float wy = sy - (float)y0i;
    const float wx = sx - (float)x0i;
    const float omwx = 1.f - wx, omwy = 1.f - wy;

    const float* iw = instw + (size_t)(b * 8 + m) * 4096;
    const float v00 = iw[y0i * 64 + x0i];
    const float v01 = iw[y0i * 64 + x1i];
    const float v10 = iw[y1i * 64 + x0i];
    const float v11 = iw[y1i * 64 + x1i];
    const float rwv = (v00 * omwx + v01 * wx) * omwy + (v10 * omwx + v11 * wx) * wy;
    if (!(rwv > 0.f)) continue;   // rmask
    const float e = expf(rwv);
    denom += e;

    const float* fb = IF + (size_t)b * 2097152 + (size_t)c * 8 + m;
    const float t00 = fb[(size_t)y0i * 32768 + (size_t)x0i * 512];
    const float t01 = fb[(size_t)y0i * 32768 + (size_t)x1i * 512];
    const float t10 = fb[(size_t)y1i * 32768 + (size_t)x0i * 512];
    const float t11 = fb[(size_t)y1i * 32768 + (size_t)x1i * 512];
    const float bil = (t00 * omwx + t01 * wx) * omwy + (t10 * omwx + t11 * wx) * wy;
    acc += e * bil;
  }
  out[(size_t)pid * 64 + c] = acc / denom;
}

// ---------------------------------------------------------------------------
extern "C" void kernel_launch(void* const* d_in, const int* in_sizes, int n_in,
                              void* d_out, int out_size, void* d_ws, size_t ws_size,
                              hipStream_t stream)
{
  const float* IF   = (const float*)d_in[0];   // [10,64,64,64,8]
  const float* BG   = (const float*)d_in[1];   // [10,128,128,64]
  const float* BBOX = (const float*)d_in[2];   // [10,4,8]
  // d_in[3] mrcnn_mask: unused by the reference forward
  const float* w1i = (const float*)d_in[4];
  const float* b1i = (const float*)d_in[5];
  const float* w2i = (const float*)d_in[6];
  const float* b2i = (const float*)d_in[7];
  const float* w1b = (const float*)d_in[8];
  const float* b1b = (const float*)d_in[9];
  const float* w2b = (const float*)d_in[10];
  const float* b2b = (const float*)d_in[11];
  const int* objn  = (const int*)d_in[12];
  float* out = (float*)d_out;

  char* wsb = (char*)d_ws;
  float*          hbuf  = (float*)(wsb);                        // 83,886,080 B
  unsigned short* wBi3  = (unsigned short*)(wsb + 83886080);    // 221,184 B
  unsigned short* wBb3  = (unsigned short*)(wsb + 84107264);    // 221,184 B
  float*          instw = (float*)(wsb + 84328448);             // 1,310,720 B
  float*          bgw   = (float*)(wsb + 85639168);             // 655,360 B -> 86.3 MB

  prep_w3<<<144, 256, 0, stream>>>(w1i, wBi3);
  prep_w3<<<144, 256, 0, stream>>>(w1b, wBb3);

  // instance branch: conv1 (fused gather+split) -> conv2
  conv1_mfma3<true><<<80 * 64, 256, 0, stream>>>(IF, wBi3, b1i, hbuf, 80, 64, 64);
  conv2_k<<<80 * 4 * 4, 256, 0, stream>>>(hbuf, w2i, b2i, instw, 80, 64, 64);
  // bg branch (reuses hbuf)
  conv1_mfma3<false><<<10 * 128 * 2, 256, 0, stream>>>(BG, wBb3, b1b, hbuf, 10, 128, 128);
  conv2_k<<<10 * 8 * 8, 256, 0, stream>>>(hbuf, w2b, b2b, bgw, 10, 128, 128);
  // fused resize + softmax composition
  compose_k<<<163840 / 4, 256, 0, stream>>>(IF, BG, BBOX, objn, instw, bgw, out);
}